// Round 12
// baseline (71.104 us; speedup 1.0000x reference)
//
#include <hip/hip_runtime.h>
#include <hip/hip_bf16.h>
#include <math.h>

// Problem constants (fixed by the reference setup_inputs)
#define NROWS 2048
#define KROWS 256
#define DDIM  512

typedef __attribute__((ext_vector_type(8))) short short8;
typedef __attribute__((ext_vector_type(4))) short short4v;
typedef __attribute__((ext_vector_type(4))) float f32x4;

// Workspace layout (bytes) — bf16 P/A stored in MFMA-fragment order:
//   PT [K/16][16][64] short8 : @0        (262144 B)
//   AT [K/16][16][64] short8 : @262144   (262144 B)
//   SC [K] float4            : @524288   (4096 B)   {p2, pa, na, kc}
//   CNT unsigned             : @528384   (4 B)      prep-arrival counter
#define AB_BYTE   262144
#define SC_FOFF   131072   // float offset
#define CNT_BYTE  528384

__device__ inline short f2bfs(float f) {
    // fp32 -> bf16 RNE (inputs are finite)
    unsigned u = __float_as_uint(f);
    u += 0x7fffu + ((u >> 16) & 1u);
    return (short)(u >> 16);
}

__device__ inline float wave_reduce_sum(float v) {
    #pragma unroll
    for (int off = 32; off > 0; off >>= 1)
        v += __shfl_xor(v, off, 64);
    return v;
}

// SINGLE DISPATCH: 512 blocks x 256 threads, __launch_bounds__(256,2) ->
// 2 blocks/CU capacity = 512 resident slots >= 512 blocks, so every block is
// resident regardless of dispatch order and the producer spin cannot deadlock.
// Blocks 0..63: run P/A/SC prep (one k per wave), __threadfence, atomicAdd.
// ALL blocks: stage their X tile (depends only on x -> overlaps prep), then
// acquire-spin on the counter, then P/A fragment loads + MFMA + epilogue.
// C/D: col = lane&15 (class), row = (lane>>4)*4 + reg (m)   [m89 verified]
__global__ __launch_bounds__(256, 2) void hmlr_one(
        const float* __restrict__ x,
        const float* __restrict__ a_vals,
        const float* __restrict__ p_vals,
        float* __restrict__ ws,
        float* __restrict__ out) {
    __shared__ short8 XS[16][64];    // 16KB bf16 X tile, fragment order
    __shared__ float  Y2S[16];
    __shared__ float  OT[4][16][20]; // padded transpose tile (5KB)

    const int tid  = threadIdx.x;
    const int lane = tid & 63;
    const int w    = tid >> 6;
    const int bid  = blockIdx.x;
    const int mt   = bid >> 2;           // 0..127
    const int ct   = (bid & 3) * 4 + w;  // 0..15
    const int m0   = mt * 16;
    const int c0   = ct * 16;
    const int row  = lane & 15;
    const int kg   = lane >> 4;

    unsigned* cnt = (unsigned*)((char*)ws + CNT_BYTE);

    // ---------------- prep (blocks 0..63, one k per wave) ----------------
    if (bid < 64) {
        const int k = bid * 4 + w;  // 0..255
        const float4* pv4 = (const float4*)(p_vals) + k * (DDIM / 4) + lane * 2;
        const float4* av4 = (const float4*)(a_vals) + k * (DDIM / 4) + lane * 2;
        float4 p0 = pv4[0], p1 = pv4[1];
        float4 a0 = av4[0], a1 = av4[1];

        float pn2 = p0.x*p0.x + p0.y*p0.y + p0.z*p0.z + p0.w*p0.w
                  + p1.x*p1.x + p1.y*p1.y + p1.z*p1.z + p1.w*p1.w;
        float an2 = a0.x*a0.x + a0.y*a0.y + a0.z*a0.z + a0.w*a0.w
                  + a1.x*a1.x + a1.y*a1.y + a1.z*a1.z + a1.w*a1.w;
        float pa0 = p0.x*a0.x + p0.y*a0.y + p0.z*a0.z + p0.w*a0.w
                  + p1.x*a1.x + p1.y*a1.y + p1.z*a1.z + p1.w*a1.w;

        pn2 = wave_reduce_sum(pn2);
        an2 = wave_reduce_sum(an2);
        pa0 = wave_reduce_sum(pa0);

        // expmap0 with c = 1: p = tanh(clamp(||u||,15)) * u / ||u||
        float u     = fmaxf(sqrtf(pn2), 1e-5f);
        float t     = tanhf(fminf(u, 15.0f));
        float scale = t / u;
        float p2    = scale * scale * pn2;       // ||p_poincare||^2
        float conf  = 1.0f - p2;                 // conformal factor (c=1)
        float na    = fmaxf(conf * sqrtf(an2), 1e-7f);  // max(||a_poincare||,1e-7)
        float pa    = scale * conf * pa0;        // dot(p_poincare, a_poincare)
        float lam   = 2.0f / (1.0f - fminf(p2, 0.9999f)); // 1/c - 1e-4
        float kc    = lam * na;                  // / sqrt(c) = 1

        float pf[8] = { scale*p0.x, scale*p0.y, scale*p0.z, scale*p0.w,
                        scale*p1.x, scale*p1.y, scale*p1.z, scale*p1.w };
        float af[8] = { conf*a0.x, conf*a0.y, conf*a0.z, conf*a0.w,
                        conf*a1.x, conf*a1.y, conf*a1.z, conf*a1.w };
        short8 pu, au;
        #pragma unroll
        for (int j = 0; j < 8; ++j) {
            pu[j] = f2bfs(pf[j]);
            au[j] = f2bfs(af[j]);
        }
        // fragment-order scatter: s = lane>>2, kg = lane&3, r = k&15
        short8* PT8 = (short8*)ws;
        short8* AT8 = (short8*)((char*)ws + AB_BYTE);
        const int ci = (((k >> 4) * 16 + (lane >> 2)) * 64) + (lane & 3) * 16 + (k & 15);
        PT8[ci] = pu;
        AT8[ci] = au;
        if (lane == 0)
            ((float4*)(ws + SC_FOFF))[k] = make_float4(p2, pa, na, kc);

        __threadfence();     // device-scope release of all this block's stores
        __syncthreads();     // all 4 waves' stores fenced before signaling
        if (tid == 0)
            __hip_atomic_fetch_add(cnt, 1u, __ATOMIC_RELEASE,
                                   __HIP_MEMORY_SCOPE_AGENT);
    }

    // ---- X staging (no dependency on prep -> overlaps it): fp32 -> LDS ----
    {
        const int r = tid >> 4;
        const int j = tid & 15;
        const float* xrow = x + (m0 + r) * DDIM;
        float ss = 0.0f;
        #pragma unroll
        for (int q = 0; q < 8; ++q) {
            float4 v = *(const float4*)(xrow + j * 4 + q * 64);
            ss += v.x*v.x + v.y*v.y + v.z*v.z + v.w*v.w;
            // c = q*64 + j*4 -> s = 2q + (j>>3), kg = (j>>1)&3, e = (j&1)*4
            const int sfr = 2 * q + (j >> 3);
            const int kfr = (j >> 1) & 3;
            short4v h;
            h[0] = f2bfs(v.x); h[1] = f2bfs(v.y);
            h[2] = f2bfs(v.z); h[3] = f2bfs(v.w);
            *(short4v*)((unsigned short*)&XS[sfr][kfr * 16 + r] + (j & 1) * 4) = h;
        }
        #pragma unroll
        for (int off = 1; off < 16; off <<= 1)
            ss += __shfl_xor(ss, off, 64);
        if (j == 0) Y2S[r] = ss;
    }
    __syncthreads();

    // ---- wait for prep to be published (device-scope acquire) ----
    while (__hip_atomic_load(cnt, __ATOMIC_ACQUIRE, __HIP_MEMORY_SCOPE_AGENT) < 64u)
        __builtin_amdgcn_s_sleep(2);

    // ---- P/A fragment preloads (coalesced 1KB each) ----
    const short8* PT8 = (const short8*)ws;
    const short8* AT8 = (const short8*)((const char*)ws + AB_BYTE);
    const float*  SC  = ws + SC_FOFF;
    const short8* pt = PT8 + ct * 16 * 64 + lane;
    const short8* at = AT8 + ct * 16 * 64 + lane;
    short8 pv[16], av[16];
    #pragma unroll
    for (int s = 0; s < 16; ++s) pv[s] = pt[s * 64];
    #pragma unroll
    for (int s = 0; s < 16; ++s) av[s] = at[s * 64];

    // ---- X fragments from LDS (overlaps P/A global latency) ----
    short8 xv[16];
    #pragma unroll
    for (int s = 0; s < 16; ++s) xv[s] = XS[s][lane];

    // ---- MFMA burst: 4 independent chains of depth 8 ----
    f32x4 aP[2] = {{0.f,0.f,0.f,0.f},{0.f,0.f,0.f,0.f}};
    f32x4 aA[2] = {{0.f,0.f,0.f,0.f},{0.f,0.f,0.f,0.f}};
    #pragma unroll
    for (int s = 0; s < 16; ++s) {
        aP[s & 1] = __builtin_amdgcn_mfma_f32_16x16x32_bf16(xv[s], pv[s], aP[s & 1], 0, 0, 0);
        aA[s & 1] = __builtin_amdgcn_mfma_f32_16x16x32_bf16(xv[s], av[s], aA[s & 1], 0, 0, 0);
    }
    f32x4 accP = aP[0] + aP[1];
    f32x4 accA = aA[0] + aA[1];

    // ---- fused epilogue -> padded LDS transpose ----
    const int c = c0 + row;
    f32x4 sc = *(const f32x4*)(SC + 4 * c);
    const float p2 = sc[0], pa = sc[1], na = sc[2], kc = sc[3];
    #pragma unroll
    for (int j = 0; j < 4; ++j) {
        const int mloc  = kg * 4 + j;
        const float y2n = Y2S[mloc];
        const float xpv = accP[j];
        const float xav = accA[j];
        // mobius_addition_batch(-p, x): xy = -xp
        const float alpha = 1.0f - 2.0f * xpv + y2n;       // 1 + 2c*xy + c*y2
        const float beta  = 1.0f - p2;                     // 1 - c*||p||^2
        const float gam   = 1.0f - 2.0f * xpv + p2 * y2n;  // denom
        const float gi    = __builtin_amdgcn_rcpf(gam + 1e-5f);
        const float num   = 2.0f * (beta * xav - alpha * pa) * gi;
        const float mob2  = (alpha*alpha*p2 + beta*beta*y2n
                             - 2.0f*alpha*beta*xpv) * gi * gi;
        const float den   = na * (1.0f - mob2);
        const float z     = num * __builtin_amdgcn_rcpf(den);
        // arsinh(z) = log(max(z + sqrt(1+z^2), 1e-5))
        const float arg   = fmaxf(z + __builtin_amdgcn_sqrtf(1.0f + z * z), 1e-5f);
        OT[w][mloc][row]  = kc * __logf(arg);
    }
    __syncthreads();

    // ---- coalesced store: one float4 per lane ----
    {
        const int mloc = lane >> 2;
        const int q    = lane & 3;
        float4 o = make_float4(OT[w][mloc][q * 4 + 0], OT[w][mloc][q * 4 + 1],
                               OT[w][mloc][q * 4 + 2], OT[w][mloc][q * 4 + 3]);
        *(float4*)(out + (m0 + mloc) * KROWS + c0 + q * 4) = o;
    }
}

extern "C" void kernel_launch(void* const* d_in, const int* in_sizes, int n_in,
                              void* d_out, int out_size, void* d_ws, size_t ws_size,
                              hipStream_t stream) {
    (void)in_sizes; (void)n_in; (void)out_size; (void)ws_size;
    const float* x      = (const float*)d_in[0];
    const float* a_vals = (const float*)d_in[1];
    const float* p_vals = (const float*)d_in[2];
    float* ws  = (float*)d_ws;
    float* out = (float*)d_out;

    // re-arm the producer counter every call (deterministic across replays)
    hipMemsetAsync((char*)d_ws + CNT_BYTE, 0, 4, stream);
    // single dispatch: 128 mt x 4 ct-groups = 512 blocks, all resident
    hmlr_one<<<512, 256, 0, stream>>>(x, a_vals, p_vals, ws, out);
}

// Round 13
// 60.418 us; speedup vs baseline: 1.1769x; 1.1769x over previous
//
#include <hip/hip_runtime.h>
#include <hip/hip_bf16.h>
#include <math.h>

// Problem constants (fixed by the reference setup_inputs)
#define NROWS 2048
#define KROWS 256
#define DDIM  512

typedef __attribute__((ext_vector_type(8))) short short8;
typedef __attribute__((ext_vector_type(4))) short short4v;
typedef __attribute__((ext_vector_type(4))) float f32x4;

// Workspace layout (bytes) — bf16 P/A stored in MFMA-fragment order:
//   PT [K/16][16][64] short8 : @0        (262144 B)
//   AT [K/16][16][64] short8 : @262144   (262144 B)
//   SC [K] float4            : @524288   (4096 B)   {p2, pa, na, kc}
//   CNT unsigned[4] @64B stride : @528384 (256 B)   per-ct-group arrival counters
#define AB_BYTE   262144
#define SC_FOFF   131072   // float offset
#define CNT_BYTE  528384

__device__ inline short f2bfs(float f) {
    // fp32 -> bf16 RNE (inputs are finite)
    unsigned u = __float_as_uint(f);
    u += 0x7fffu + ((u >> 16) & 1u);
    return (short)(u >> 16);
}

__device__ inline float wave_reduce_sum(float v) {
    #pragma unroll
    for (int off = 32; off > 0; off >>= 1)
        v += __shfl_xor(v, off, 64);
    return v;
}

// SINGLE COMPUTE DISPATCH: 512 blocks x 256 threads, __launch_bounds__(256,2)
// -> 2 blocks/CU x 256 CU = 512 resident slots >= 512 blocks: all blocks are
// co-resident, so the producer wait cannot deadlock.
// Blocks 0..63 first run P/A/SC prep (one k per wave) and release-signal
// their ct-group counter (block b produces for group b>>4; 16 blocks/group).
// ALL blocks then stage their X tile (depends only on x -> overlaps prep),
// and ONLY thread 0 polls the group counter (relaxed + s_sleep backoff, one
// acquire load on exit) -> no polling storm. Then P/A fragment loads + MFMA
// + fused epilogue + coalesced stores (R11 body).
// C/D: col = lane&15 (class), row = (lane>>4)*4 + reg (m)   [m89 verified]
__global__ __launch_bounds__(256, 2) void hmlr_one(
        const float* __restrict__ x,
        const float* __restrict__ a_vals,
        const float* __restrict__ p_vals,
        float* __restrict__ ws,
        float* __restrict__ out) {
    __shared__ short8 XS[16][64];    // 16KB bf16 X tile, fragment order
    __shared__ float  Y2S[16];
    __shared__ float  OT[4][16][20]; // padded transpose tile (5KB)

    const int tid  = threadIdx.x;
    const int lane = tid & 63;
    const int w    = tid >> 6;
    const int bid  = blockIdx.x;
    const int mt   = bid >> 2;           // 0..127
    const int g    = bid & 3;            // ct-group this block consumes
    const int ct   = g * 4 + w;          // 0..15
    const int m0   = mt * 16;
    const int c0   = ct * 16;
    const int row  = lane & 15;
    const int kg   = lane >> 4;

    // ---------------- prep (blocks 0..63, one k per wave) ----------------
    if (bid < 64) {
        const int k = bid * 4 + w;  // 0..255
        const float4* pv4 = (const float4*)(p_vals) + k * (DDIM / 4) + lane * 2;
        const float4* av4 = (const float4*)(a_vals) + k * (DDIM / 4) + lane * 2;
        float4 p0 = pv4[0], p1 = pv4[1];
        float4 a0 = av4[0], a1 = av4[1];

        float pn2 = p0.x*p0.x + p0.y*p0.y + p0.z*p0.z + p0.w*p0.w
                  + p1.x*p1.x + p1.y*p1.y + p1.z*p1.z + p1.w*p1.w;
        float an2 = a0.x*a0.x + a0.y*a0.y + a0.z*a0.z + a0.w*a0.w
                  + a1.x*a1.x + a1.y*a1.y + a1.z*a1.z + a1.w*a1.w;
        float pa0 = p0.x*a0.x + p0.y*a0.y + p0.z*a0.z + p0.w*a0.w
                  + p1.x*a1.x + p1.y*a1.y + p1.z*a1.z + p1.w*a1.w;

        pn2 = wave_reduce_sum(pn2);
        an2 = wave_reduce_sum(an2);
        pa0 = wave_reduce_sum(pa0);

        // expmap0 with c = 1: p = tanh(clamp(||u||,15)) * u / ||u||
        float u     = fmaxf(sqrtf(pn2), 1e-5f);
        float t     = tanhf(fminf(u, 15.0f));
        float scale = t / u;
        float p2    = scale * scale * pn2;       // ||p_poincare||^2
        float conf  = 1.0f - p2;                 // conformal factor (c=1)
        float na    = fmaxf(conf * sqrtf(an2), 1e-7f);  // max(||a_poincare||,1e-7)
        float pa    = scale * conf * pa0;        // dot(p_poincare, a_poincare)
        float lam   = 2.0f / (1.0f - fminf(p2, 0.9999f)); // 1/c - 1e-4
        float kc    = lam * na;                  // / sqrt(c) = 1

        float pf[8] = { scale*p0.x, scale*p0.y, scale*p0.z, scale*p0.w,
                        scale*p1.x, scale*p1.y, scale*p1.z, scale*p1.w };
        float af[8] = { conf*a0.x, conf*a0.y, conf*a0.z, conf*a0.w,
                        conf*a1.x, conf*a1.y, conf*a1.z, conf*a1.w };
        short8 pu, au;
        #pragma unroll
        for (int j = 0; j < 8; ++j) {
            pu[j] = f2bfs(pf[j]);
            au[j] = f2bfs(af[j]);
        }
        // fragment-order scatter: s = lane>>2, kg = lane&3, r = k&15
        short8* PT8 = (short8*)ws;
        short8* AT8 = (short8*)((char*)ws + AB_BYTE);
        const int ci = (((k >> 4) * 16 + (lane >> 2)) * 64) + (lane & 3) * 16 + (k & 15);
        PT8[ci] = pu;
        AT8[ci] = au;
        if (lane == 0)
            ((float4*)(ws + SC_FOFF))[k] = make_float4(p2, pa, na, kc);

        __threadfence();     // device-scope release of this block's stores
        __syncthreads();     // all 4 waves fenced before signaling
        if (tid == 0) {
            unsigned* cprod = (unsigned*)((char*)ws + CNT_BYTE + (bid >> 4) * 64);
            __hip_atomic_fetch_add(cprod, 1u, __ATOMIC_RELEASE,
                                   __HIP_MEMORY_SCOPE_AGENT);
        }
    }

    // ---- X staging (no dependency on prep -> overlaps it): fp32 -> LDS ----
    {
        const int r = tid >> 4;
        const int j = tid & 15;
        const float* xrow = x + (m0 + r) * DDIM;
        float ss = 0.0f;
        #pragma unroll
        for (int q = 0; q < 8; ++q) {
            float4 v = *(const float4*)(xrow + j * 4 + q * 64);
            ss += v.x*v.x + v.y*v.y + v.z*v.z + v.w*v.w;
            // c = q*64 + j*4 -> s = 2q + (j>>3), kg = (j>>1)&3, e = (j&1)*4
            const int sfr = 2 * q + (j >> 3);
            const int kfr = (j >> 1) & 3;
            short4v h;
            h[0] = f2bfs(v.x); h[1] = f2bfs(v.y);
            h[2] = f2bfs(v.z); h[3] = f2bfs(v.w);
            *(short4v*)((unsigned short*)&XS[sfr][kfr * 16 + r] + (j & 1) * 4) = h;
        }
        #pragma unroll
        for (int off = 1; off < 16; off <<= 1)
            ss += __shfl_xor(ss, off, 64);
        if (j == 0) Y2S[r] = ss;
    }

    // ---- wait for this block's ct-group (thread 0 only; sleep backoff) ----
    {
        unsigned* cwait = (unsigned*)((char*)ws + CNT_BYTE + g * 64);
        if (tid == 0) {
            while (__hip_atomic_load(cwait, __ATOMIC_RELAXED,
                                     __HIP_MEMORY_SCOPE_AGENT) < 16u)
                __builtin_amdgcn_s_sleep(16);
            (void)__hip_atomic_load(cwait, __ATOMIC_ACQUIRE,
                                    __HIP_MEMORY_SCOPE_AGENT);
        }
        __syncthreads();     // also covers the X-staging LDS writes
        __threadfence();     // order subsequent PT/AT/SC loads after release
    }

    // ---- P/A fragment preloads (coalesced 1KB each) ----
    const short8* PT8 = (const short8*)ws;
    const short8* AT8 = (const short8*)((const char*)ws + AB_BYTE);
    const float*  SC  = ws + SC_FOFF;
    const short8* pt = PT8 + ct * 16 * 64 + lane;
    const short8* at = AT8 + ct * 16 * 64 + lane;
    short8 pv[16], av[16];
    #pragma unroll
    for (int s = 0; s < 16; ++s) pv[s] = pt[s * 64];
    #pragma unroll
    for (int s = 0; s < 16; ++s) av[s] = at[s * 64];

    // ---- X fragments from LDS (overlaps P/A global latency) ----
    short8 xv[16];
    #pragma unroll
    for (int s = 0; s < 16; ++s) xv[s] = XS[s][lane];

    // ---- MFMA burst: 4 independent chains of depth 8 ----
    f32x4 aP[2] = {{0.f,0.f,0.f,0.f},{0.f,0.f,0.f,0.f}};
    f32x4 aA[2] = {{0.f,0.f,0.f,0.f},{0.f,0.f,0.f,0.f}};
    #pragma unroll
    for (int s = 0; s < 16; ++s) {
        aP[s & 1] = __builtin_amdgcn_mfma_f32_16x16x32_bf16(xv[s], pv[s], aP[s & 1], 0, 0, 0);
        aA[s & 1] = __builtin_amdgcn_mfma_f32_16x16x32_bf16(xv[s], av[s], aA[s & 1], 0, 0, 0);
    }
    f32x4 accP = aP[0] + aP[1];
    f32x4 accA = aA[0] + aA[1];

    // ---- fused epilogue -> padded LDS transpose ----
    const int c = c0 + row;
    f32x4 sc = *(const f32x4*)(SC + 4 * c);
    const float p2 = sc[0], pa = sc[1], na = sc[2], kc = sc[3];
    #pragma unroll
    for (int j = 0; j < 4; ++j) {
        const int mloc  = kg * 4 + j;
        const float y2n = Y2S[mloc];
        const float xpv = accP[j];
        const float xav = accA[j];
        // mobius_addition_batch(-p, x): xy = -xp
        const float alpha = 1.0f - 2.0f * xpv + y2n;       // 1 + 2c*xy + c*y2
        const float beta  = 1.0f - p2;                     // 1 - c*||p||^2
        const float gam   = 1.0f - 2.0f * xpv + p2 * y2n;  // denom
        const float gi    = __builtin_amdgcn_rcpf(gam + 1e-5f);
        const float num   = 2.0f * (beta * xav - alpha * pa) * gi;
        const float mob2  = (alpha*alpha*p2 + beta*beta*y2n
                             - 2.0f*alpha*beta*xpv) * gi * gi;
        const float den   = na * (1.0f - mob2);
        const float z     = num * __builtin_amdgcn_rcpf(den);
        // arsinh(z) = log(max(z + sqrt(1+z^2), 1e-5))
        const float arg   = fmaxf(z + __builtin_amdgcn_sqrtf(1.0f + z * z), 1e-5f);
        OT[w][mloc][row]  = kc * __logf(arg);
    }
    __syncthreads();

    // ---- coalesced store: one float4 per lane ----
    {
        const int mloc = lane >> 2;
        const int q    = lane & 3;
        float4 o = make_float4(OT[w][mloc][q * 4 + 0], OT[w][mloc][q * 4 + 1],
                               OT[w][mloc][q * 4 + 2], OT[w][mloc][q * 4 + 3]);
        *(float4*)(out + (m0 + mloc) * KROWS + c0 + q * 4) = o;
    }
}

extern "C" void kernel_launch(void* const* d_in, const int* in_sizes, int n_in,
                              void* d_out, int out_size, void* d_ws, size_t ws_size,
                              hipStream_t stream) {
    (void)in_sizes; (void)n_in; (void)out_size; (void)ws_size;
    const float* x      = (const float*)d_in[0];
    const float* a_vals = (const float*)d_in[1];
    const float* p_vals = (const float*)d_in[2];
    float* ws  = (float*)d_ws;
    float* out = (float*)d_out;

    // re-arm the 4 per-group counters every call (deterministic across replays)
    hipMemsetAsync((char*)d_ws + CNT_BYTE, 0, 256, stream);
    // single compute dispatch: 128 mt x 4 ct-groups = 512 blocks, all resident
    hmlr_one<<<512, 256, 0, stream>>>(x, a_vals, p_vals, ws, out);
}

// Round 14
// 15.442 us; speedup vs baseline: 4.6045x; 3.9126x over previous
//
#include <hip/hip_runtime.h>
#include <hip/hip_bf16.h>
#include <math.h>

// Problem constants (fixed by the reference setup_inputs)
#define NROWS 2048
#define KROWS 256
#define DDIM  512

typedef __attribute__((ext_vector_type(8))) short short8;
typedef __attribute__((ext_vector_type(4))) short short4v;
typedef __attribute__((ext_vector_type(4))) float f32x4;

// Workspace layout (bytes) — bf16 P/A stored in MFMA-fragment order:
//   chunk index ((tile*16 + s)*64 + kg*16 + r) holds
//   T[tile*16 + r][s*32 + kg*8 .. +8] as short8, so a wave load at
//   base + s*64chunks + lane is 1KB coalesced and fragment-ready.
//   PT [K/16][16][64] short8 : @0        (262144 B)
//   AT [K/16][16][64] short8 : @262144   (262144 B)
//   SC [K] float4            : @524288   (4096 B)   {p2, pa, na, kc}
#define AB_BYTE   262144
#define SC_FOFF   131072   // float offset

__device__ inline short f2bfs(float f) {
    // fp32 -> bf16 RNE (inputs are finite)
    unsigned u = __float_as_uint(f);
    u += 0x7fffu + ((u >> 16) & 1u);
    return (short)(u >> 16);
}

__device__ inline float wave_reduce_sum(float v) {
    #pragma unroll
    for (int off = 32; off > 0; off >>= 1)
        v += __shfl_xor(v, off, 64);
    return v;
}

// Prep: 256 blocks x 64 threads, ONE k per block (full-GPU, minimal tail).
// expmap0 + conformal prep -> bf16 P/A in fragment order + SC scalars.
__global__ __launch_bounds__(64) void hmlr_prep(
        const float* __restrict__ a_vals,
        const float* __restrict__ p_vals,
        float* __restrict__ ws) {
    const int lane = threadIdx.x;
    const int k    = blockIdx.x;  // 0..255

    const float4* pv4 = (const float4*)(p_vals) + k * (DDIM / 4) + lane * 2;
    const float4* av4 = (const float4*)(a_vals) + k * (DDIM / 4) + lane * 2;
    float4 p0 = pv4[0], p1 = pv4[1];
    float4 a0 = av4[0], a1 = av4[1];

    float pn2 = p0.x*p0.x + p0.y*p0.y + p0.z*p0.z + p0.w*p0.w
              + p1.x*p1.x + p1.y*p1.y + p1.z*p1.z + p1.w*p1.w;
    float an2 = a0.x*a0.x + a0.y*a0.y + a0.z*a0.z + a0.w*a0.w
              + a1.x*a1.x + a1.y*a1.y + a1.z*a1.z + a1.w*a1.w;
    float pa0 = p0.x*a0.x + p0.y*a0.y + p0.z*a0.z + p0.w*a0.w
              + p1.x*a1.x + p1.y*a1.y + p1.z*a1.z + p1.w*a1.w;

    pn2 = wave_reduce_sum(pn2);
    an2 = wave_reduce_sum(an2);
    pa0 = wave_reduce_sum(pa0);

    // expmap0 with c = 1: p = tanh(clamp(||u||,15)) * u / ||u||
    float u     = fmaxf(sqrtf(pn2), 1e-5f);
    float t     = tanhf(fminf(u, 15.0f));
    float scale = t / u;
    float p2    = scale * scale * pn2;       // ||p_poincare||^2
    float conf  = 1.0f - p2;                 // conformal factor (c=1)
    float na    = fmaxf(conf * sqrtf(an2), 1e-7f);  // max(||a_poincare||, 1e-7)
    float pa    = scale * conf * pa0;        // dot(p_poincare, a_poincare)
    float lam   = 2.0f / (1.0f - fminf(p2, 0.9999f)); // 1/c - 1e-4 = 0.9999
    float kc    = lam * na;                  // / sqrt(c) = 1

    float pf[8] = { scale*p0.x, scale*p0.y, scale*p0.z, scale*p0.w,
                    scale*p1.x, scale*p1.y, scale*p1.z, scale*p1.w };
    float af[8] = { conf*a0.x, conf*a0.y, conf*a0.z, conf*a0.w,
                    conf*a1.x, conf*a1.y, conf*a1.z, conf*a1.w };
    short8 pu, au;
    #pragma unroll
    for (int j = 0; j < 8; ++j) {
        pu[j] = f2bfs(pf[j]);
        au[j] = f2bfs(af[j]);
    }
    // fragment-order scatter: s = lane>>2, kg = lane&3, r = k&15
    short8* PT8 = (short8*)ws;
    short8* AT8 = (short8*)((char*)ws + AB_BYTE);
    const int ci = (((k >> 4) * 16 + (lane >> 2)) * 64) + (lane & 3) * 16 + (k & 15);
    PT8[ci] = pu;
    AT8[ci] = au;
    if (lane == 0)
        ((float4*)(ws + SC_FOFF))[k] = make_float4(p2, pa, na, kc);
}

// Main MFMA kernel: block = 2 mt x 4 ct, 8 waves (512 threads), 256 blocks
// = exactly 1 block/CU (no tail, 2 waves/SIMD as before).
// Per-CU unique global bytes drop 320KB -> 192KB vs the 4-wave version:
// X (64KB fp32) staged ONCE for two m-tiles, and each ct's P/A fragments
// (32KB) are read by TWO waves at identical addresses (L1 broadcast).
// ctg = bid&3 with XCD = bid%8 -> one ct-group per XCD (L2-resident).
// Wave w: ct_local = w>>1, mt_local = w&1.
// C/D: col = lane&15 (class), row = (lane>>4)*4 + reg (m)   [m89 verified]
__global__ __launch_bounds__(512, 2) void hmlr_main(
        const float* __restrict__ x,
        const float* __restrict__ ws,
        float* __restrict__ out) {
    __shared__ short8 XS[2][16][64];  // 32KB bf16 X tiles, fragment order
    __shared__ float  Y2S[32];
    __shared__ float  OT[8][16][20];  // padded transpose tiles (10KB)

    const int tid  = threadIdx.x;
    const int lane = tid & 63;
    const int w    = tid >> 6;            // 0..7
    const int ctl  = w >> 1;              // 0..3
    const int mtl  = w & 1;               // 0..1
    const int bid  = blockIdx.x;
    const int mtg  = bid >> 2;            // 0..63
    const int ctg  = bid & 3;             // 0..3
    const int ct   = ctg * 4 + ctl;       // 0..15
    const int m0   = (mtg * 2 + mtl) * 16;
    const int c0   = ct * 16;
    const int row  = lane & 15;
    const int kg   = lane >> 4;

    const short8* PT8 = (const short8*)ws;
    const short8* AT8 = (const short8*)((const char*)ws + AB_BYTE);
    const float*  SC  = ws + SC_FOFF;

    // ---- issue P/A fragment preloads (overlap with X staging) ----
    const short8* pt = PT8 + ct * 16 * 64 + lane;
    const short8* at = AT8 + ct * 16 * 64 + lane;
    short8 pv[16], av[16];
    #pragma unroll
    for (int s = 0; s < 16; ++s) pv[s] = pt[s * 64];
    #pragma unroll
    for (int s = 0; s < 16; ++s) av[s] = at[s * 64];

    // ---- cooperative X staging: 32 rows fp32 -> bf16 fragment LDS + y2 ----
    // thread t: row r = t>>4 (0..31), within-row lane j = t&15; reads float4
    // at cols j*4 + q*64 -> dense 256B per 16 threads per q.
    {
        const int r = tid >> 4;
        const int j = tid & 15;
        const float* xrow = x + ((mtg * 2) * 16 + r) * DDIM;
        float ss = 0.0f;
        #pragma unroll
        for (int q = 0; q < 8; ++q) {
            float4 v = *(const float4*)(xrow + j * 4 + q * 64);
            ss += v.x*v.x + v.y*v.y + v.z*v.z + v.w*v.w;
            // c = q*64 + j*4 -> s = 2q + (j>>3), kg = (j>>1)&3, e = (j&1)*4
            const int sfr = 2 * q + (j >> 3);
            const int kfr = (j >> 1) & 3;
            short4v h;
            h[0] = f2bfs(v.x); h[1] = f2bfs(v.y);
            h[2] = f2bfs(v.z); h[3] = f2bfs(v.w);
            *(short4v*)((unsigned short*)&XS[r >> 4][sfr][kfr * 16 + (r & 15)]
                        + (j & 1) * 4) = h;
        }
        // row-sum over the 16 threads of this row (contiguous in one wave)
        #pragma unroll
        for (int off = 1; off < 16; off <<= 1)
            ss += __shfl_xor(ss, off, 64);
        if (j == 0) Y2S[r] = ss;
    }
    __syncthreads();

    // ---- X fragments from LDS (consecutive b128, conflict-free) ----
    short8 xv[16];
    #pragma unroll
    for (int s = 0; s < 16; ++s) xv[s] = XS[mtl][s][lane];

    // ---- MFMA burst: 4 independent chains of depth 8 ----
    f32x4 aP[2] = {{0.f,0.f,0.f,0.f},{0.f,0.f,0.f,0.f}};
    f32x4 aA[2] = {{0.f,0.f,0.f,0.f},{0.f,0.f,0.f,0.f}};
    #pragma unroll
    for (int s = 0; s < 16; ++s) {
        aP[s & 1] = __builtin_amdgcn_mfma_f32_16x16x32_bf16(xv[s], pv[s], aP[s & 1], 0, 0, 0);
        aA[s & 1] = __builtin_amdgcn_mfma_f32_16x16x32_bf16(xv[s], av[s], aA[s & 1], 0, 0, 0);
    }
    f32x4 accP = aP[0] + aP[1];
    f32x4 accA = aA[0] + aA[1];

    // ---- fused epilogue -> padded LDS transpose (wave-local region) ----
    const int c = c0 + row;
    f32x4 sc = *(const f32x4*)(SC + 4 * c);
    const float p2 = sc[0], pa = sc[1], na = sc[2], kc = sc[3];
    #pragma unroll
    for (int j = 0; j < 4; ++j) {
        const int mloc  = kg * 4 + j;
        const float y2n = Y2S[mtl * 16 + mloc];
        const float xpv = accP[j];
        const float xav = accA[j];
        // mobius_addition_batch(-p, x): xy = -xp
        const float alpha = 1.0f - 2.0f * xpv + y2n;       // 1 + 2c*xy + c*y2
        const float beta  = 1.0f - p2;                     // 1 - c*||p||^2
        const float gam   = 1.0f - 2.0f * xpv + p2 * y2n;  // denom
        const float gi    = __builtin_amdgcn_rcpf(gam + 1e-5f);
        const float num   = 2.0f * (beta * xav - alpha * pa) * gi;
        const float mob2  = (alpha*alpha*p2 + beta*beta*y2n
                             - 2.0f*alpha*beta*xpv) * gi * gi;
        const float den   = na * (1.0f - mob2);
        const float z     = num * __builtin_amdgcn_rcpf(den);
        // arsinh(z) = log(max(z + sqrt(1+z^2), 1e-5))
        const float arg   = fmaxf(z + __builtin_amdgcn_sqrtf(1.0f + z * z), 1e-5f);
        OT[w][mloc][row]  = kc * __logf(arg);
    }
    // no barrier needed: OT[w] is written and read only by wave w

    // ---- coalesced store: one float4 per lane ----
    {
        const int mloc = lane >> 2;
        const int q    = lane & 3;
        float4 o = make_float4(OT[w][mloc][q * 4 + 0], OT[w][mloc][q * 4 + 1],
                               OT[w][mloc][q * 4 + 2], OT[w][mloc][q * 4 + 3]);
        *(float4*)(out + (m0 + mloc) * KROWS + c0 + q * 4) = o;
    }
}

extern "C" void kernel_launch(void* const* d_in, const int* in_sizes, int n_in,
                              void* d_out, int out_size, void* d_ws, size_t ws_size,
                              hipStream_t stream) {
    (void)in_sizes; (void)n_in; (void)out_size; (void)ws_size;
    const float* x      = (const float*)d_in[0];
    const float* a_vals = (const float*)d_in[1];
    const float* p_vals = (const float*)d_in[2];
    float* ws  = (float*)d_ws;
    float* out = (float*)d_out;

    // prep: 256 blocks x 64 threads, one k per block (full GPU, short tail)
    hmlr_prep<<<256, 64, 0, stream>>>(a_vals, p_vals, ws);
    // main: 64 mt-groups x 4 ct-groups = 256 blocks x 512 threads (1/CU)
    hmlr_main<<<256, 512, 0, stream>>>(x, ws, out);
}